// Round 1
// baseline (435.210 us; speedup 1.0000x reference)
//
#include <hip/hip_runtime.h>
#include <stdint.h>

// FLASH — R7: 256x256 8-phase counted-vmcnt MFMA kernel (T2+T3+T4+T5+T1)
//  for modes 0/2/3; old 128x128 kernel retained for modes 1 (K=128) and 4 (N=128).
//
//  gemm256 schedule (per K-tile t, buffers buf=t&1, quadrants P1..P4):
//   P1=(ms0,ns0): stage (t+1):A0 and (t+1):B1 -> buf^1
//   P2=(ms1,ns0): no stage
//   P3=(ms1,ns1): stage (t+2):B0 -> buf   (B0 of tile t freed after P2)
//   P4=(ms0,ns1): stage (t+2):A1 -> buf   (A1 of tile t freed after P3)
//                 s_waitcnt vmcnt(4)  (guarantees tile t+1 fully landed; newest
//                 2 half-tiles = (t+2):B0,(t+2):A1 may stay in flight)
//  Each phase: 12x ds_read_b128 ; stage ; s_barrier ; setprio(1) ; 8x MFMA ;
//  setprio(0) ; [vmcnt] ; s_barrier.
//  LDS swizzle: physical 16B chunk p of row r holds logical chunk p ^ (r&7),
//  realized via per-lane global column selection (gload_lds LDS dst linear).

#define H_DIM  1024
#define E_DIM  2048
#define SD     128
#define B_SZ   4
#define S_LEN  2048
#define M_TOT  (B_SZ * S_LEN)          // 8192
#define F_DIM  (2 * E_DIM + SD)        // 4224

typedef _Float16 f16;
typedef __attribute__((ext_vector_type(4))) _Float16 f16x4;
typedef __attribute__((ext_vector_type(8))) _Float16 f16x8;
typedef __attribute__((ext_vector_type(16))) float f32x16;

__device__ __forceinline__ float silu_f(float x) { return x / (1.f + __expf(-x)); }

__device__ __forceinline__ void gload16(const void* g, void* l) {
  __builtin_amdgcn_global_load_lds(
      (const __attribute__((address_space(1))) void*)(uintptr_t)g,
      (__attribute__((address_space(3))) void*)(uint32_t)(uintptr_t)l,
      16, 0, 0);
}

// ---------------- prep kernels ----------------
__global__ __launch_bounds__(256) void cast_f16_k(const float* __restrict__ src,
                                                  f16* __restrict__ dst, long n) {
  long i = ((long)blockIdx.x * 256 + threadIdx.x) * 4;
  if (i < n) {
    float4 v = *(const float4*)(src + i);
    f16x4 h; h[0] = (f16)v.x; h[1] = (f16)v.y; h[2] = (f16)v.z; h[3] = (f16)v.w;
    *(f16x4*)(dst + i) = h;
  }
}

__global__ __launch_bounds__(256) void transpose_cast_k(const float* __restrict__ src,
                                                        f16* __restrict__ dst, int R, int C) {
  __shared__ float tile[32][33];
  int c0 = blockIdx.x * 32, r0 = blockIdx.y * 32;
  int tx = threadIdx.x & 31, ty = threadIdx.x >> 5;
  for (int i = ty; i < 32; i += 8) tile[i][tx] = src[(long)(r0 + i) * C + c0 + tx];
  __syncthreads();
  for (int i = ty; i < 32; i += 8) dst[(long)(c0 + i) * R + r0 + tx] = (f16)tile[tx][i];
}

// ---------------- 256x256 8-phase GEMM ----------------
// A: [m][k] f16 (row stride K), B: [n][k] f16 (row stride K).
//  MODE 0: K=1024, u/v epilogue.  MODE 2: K=2048, p = u*(sq@v^T).
//  MODE 3: K=2048, out fp32 = acc*2^-34 + b_out.
template <int MODE>
__global__ __launch_bounds__(512, 2) void gemm256(
    const f16* __restrict__ Ag, const f16* __restrict__ Bg,
    float* __restrict__ F0, f16* __restrict__ O0, f16* __restrict__ O1,
    const f16* __restrict__ I0, const float* __restrict__ C0)
{
  constexpr int K  = (MODE == 0) ? H_DIM : 2048;
  constexpr int NT = K / 64;

  __shared__ f16 As[2][256][64];   // 64 KB
  __shared__ f16 Bs[2][256][64];   // 64 KB

  const int t    = threadIdx.x;
  const int w    = t >> 6;            // 0..7
  const int lane = t & 63;
  const int lo5  = lane & 31;
  const int hi   = lane >> 5;
  const int wm   = w >> 2;            // 0..1
  const int wn   = w & 3;             // 0..3

  // T1: bijective XCD swizzle on the (x,y) plane (nwg % 8 == 0 for all modes)
  const int gx  = gridDim.x;
  const int nwg = gx * gridDim.y;
  const int lin = blockIdx.y * gx + blockIdx.x;
  const int cpx = nwg >> 3;
  const int wg  = (lin & 7) * cpx + (lin >> 3);
  const int n0  = (wg % gx) * 256;
  const int m0  = (wg / gx) * 256;
  const long z  = blockIdx.z;

  const f16* A = Ag + (MODE == 2 ? z * (long)S_LEN * S_LEN : 0);
  const f16* B = Bg + (MODE == 2 ? z * (long)E_DIM * S_LEN : 0);

  // stage one half-tile (128 rows x 64 k): 2 x gload16 per thread.
  // wave-uniform LDS base; global column pre-swizzled: chunk lc = (lane&7)^(lane>>3)
  auto stageA = [&](int bb, int half, int kt2) {
    const f16* g0 = A + (long)(m0 + half * 128) * K + kt2 * 64;
    f16* lb = &As[bb][half * 128][0];
#pragma unroll
    for (int j = 0; j < 2; j++) {
      int grp = (j << 3) + w;                       // 0..15
      int rl  = (grp << 3) + (lane >> 3);           // 0..127
      gload16(g0 + (long)rl * K + (((lane & 7) ^ (lane >> 3)) << 3), lb + (grp << 9));
    }
  };
  auto stageB = [&](int bb, int half, int kt2) {
    const f16* g0 = B + (long)(n0 + half * 128) * K + kt2 * 64;
    f16* lb = &Bs[bb][half * 128][0];
#pragma unroll
    for (int j = 0; j < 2; j++) {
      int grp = (j << 3) + w;
      int rl  = (grp << 3) + (lane >> 3);
      gload16(g0 + (long)rl * K + (((lane & 7) ^ (lane >> 3)) << 3), lb + (grp << 9));
    }
  };

  f32x16 acc[4][2] = {};

  // prologue: tile0 fully (buf0) + tile1:B0,A1 (buf1); wait tile0, barrier.
  stageA(0, 0, 0); stageA(0, 1, 0); stageB(0, 0, 0); stageB(0, 1, 0);
  stageB(1, 0, 1); stageA(1, 1, 1);
  asm volatile("s_waitcnt vmcnt(4)" ::: "memory");
  __builtin_amdgcn_s_barrier();

#define PHASE(Q, MS, NS, STAGE_STMT, TAIL_STMT) do {                            \
    f16x8 av0_[4], av1_[4], bv_[4];                                             \
    const int ar_ = (MS) * 128 + wm * 64 + lo5;                                 \
    const int br_ = (NS) * 128 + wn * 32 + lo5;                                 \
    _Pragma("unroll")                                                           \
    for (int ksl = 0; ksl < 4; ksl++) {                                         \
      const int pc_ = (((ksl << 1) + hi) ^ (lo5 & 7)) << 3;                     \
      av0_[ksl] = *(const f16x8*)&As[bf][ar_][pc_];                             \
      av1_[ksl] = *(const f16x8*)&As[bf][ar_ + 32][pc_];                        \
      bv_[ksl]  = *(const f16x8*)&Bs[bf][br_][pc_];                             \
    }                                                                           \
    STAGE_STMT;                                                                 \
    __builtin_amdgcn_s_barrier();                                               \
    __builtin_amdgcn_s_setprio(1);                                              \
    _Pragma("unroll")                                                           \
    for (int ksl = 0; ksl < 4; ksl++) {                                         \
      acc[Q][0] = __builtin_amdgcn_mfma_f32_32x32x16_f16(av0_[ksl], bv_[ksl],   \
                                                         acc[Q][0], 0, 0, 0);   \
      acc[Q][1] = __builtin_amdgcn_mfma_f32_32x32x16_f16(av1_[ksl], bv_[ksl],   \
                                                         acc[Q][1], 0, 0, 0);   \
    }                                                                           \
    __builtin_amdgcn_s_setprio(0);                                              \
    TAIL_STMT;                                                                  \
    __builtin_amdgcn_s_barrier();                                               \
  } while (0)

  for (int kt = 0; kt < NT; ++kt) {
    const int bf = kt & 1;
    const bool s1 = (kt + 1 < NT);
    const bool s2 = (kt + 2 < NT);
    PHASE(0, 0, 0, if (s1) { stageA(bf ^ 1, 0, kt + 1); stageB(bf ^ 1, 1, kt + 1); }, );
    PHASE(1, 1, 0, , );
    PHASE(2, 1, 1, if (s2) { stageB(bf, 0, kt + 2); }, );
    PHASE(3, 0, 1, if (s2) { stageA(bf, 1, kt + 2); },
          if (s2) { asm volatile("s_waitcnt vmcnt(4)" ::: "memory"); }
          else    { asm volatile("s_waitcnt vmcnt(0)" ::: "memory"); });
  }
#undef PHASE

  // C/D (32x32): col = lane&31, row = (reg&3) + 8*(reg>>2) + 4*hi
#pragma unroll
  for (int q = 0; q < 4; q++) {
    const int ms = (q == 1 || q == 2) ? 1 : 0;
    const int ns = q >> 1;
#pragma unroll
    for (int im = 0; im < 2; im++) {
      const int gc    = n0 + ns * 128 + wn * 32 + lo5;
      const int rbase = m0 + ms * 128 + wm * 64 + im * 32 + (hi << 2);
      if (MODE == 0) {
        const float bias = C0[gc];
        if (n0 < E_DIM) {            // u region: fp16 row-major [M][E]
#pragma unroll
          for (int g = 0; g < 4; g++)
#pragma unroll
            for (int rr = 0; rr < 4; rr++) {
              int gr = rbase + (g << 3) + rr;
              O0[(long)gr * E_DIM + gc] = (f16)silu_f(acc[q][im][g * 4 + rr] + bias);
            }
        } else {                     // v region: fp16 transposed [b][e][s]
#pragma unroll
          for (int g = 0; g < 4; g++) {
            int gr0 = rbase + (g << 3);
            int b   = gr0 >> 11;
            int s0  = gr0 & (S_LEN - 1);
            f16x4 pk;
#pragma unroll
            for (int rr = 0; rr < 4; rr++) pk[rr] = (f16)silu_f(acc[q][im][g * 4 + rr] + bias);
            *(f16x4*)&O1[((long)b * E_DIM + (gc - E_DIM)) * S_LEN + s0] = pk;
          }
        }
      } else if (MODE == 2) {        // p = fp16(u * attn_v_scaled)
        const long rowoff = z * S_LEN;
#pragma unroll
        for (int g = 0; g < 4; g++)
#pragma unroll
          for (int rr = 0; rr < 4; rr++) {
            int gr = rbase + (g << 3) + rr;
            long idx = (rowoff + gr) * (long)E_DIM + gc;
            O0[idx] = (f16)((float)I0[idx] * acc[q][im][g * 4 + rr]);
          }
      } else {                       // MODE 3: out = acc*2^-34 + b_out (fp32)
        const float bias = C0[gc];
#pragma unroll
        for (int g = 0; g < 4; g++)
#pragma unroll
          for (int rr = 0; rr < 4; rr++) {
            int gr = rbase + (g << 3) + rr;
            F0[(long)gr * H_DIM + gc] = acc[q][im][g * 4 + rr] * (1.0f / 17179869184.0f) + bias;
          }
      }
    }
  }
}

// ---------------- old 128x128 kernel (modes 1 and 4 only) ----------------
template <int MODE>
__global__ __launch_bounds__(256) void mfma_gemm(
    const f16* __restrict__ Ag, const f16* __restrict__ Bg,
    float* __restrict__ F0, f16* __restrict__ H0, const f16* __restrict__ H1,
    f16* __restrict__ H2, f16* __restrict__ H3,
    const float* __restrict__ C0, const float* __restrict__ C1,
    const float* __restrict__ C2)
{
  constexpr int K   = (MODE == 1) ? SD : H_DIM;
  constexpr int LDA = K, LDB = K;

  __shared__ f16 As[2][128][32];
  __shared__ f16 Bs[2][128][32];

  const int t    = threadIdx.x;
  const int w    = t >> 6;
  const int lane = t & 63;
  const int lo5  = lane & 31;
  const int hi   = lane >> 5;
  const int wy   = w >> 1, wx = w & 1;
  const int m0   = blockIdx.y * 128;
  const int n0   = blockIdx.x * 128;
  const long z   = blockIdx.z;

  const f16* A = Ag + (MODE == 1 ? z * (long)S_LEN * SD : 0);
  const f16* B = Bg + (MODE == 1 ? z * (long)S_LEN * SD : 0);

  const int srow = lane >> 2;
  const int scol = (((lane & 3) ^ ((srow >> 1) & 3))) * 8;
  const int rsw  = (lo5 >> 1) & 3;

  f32x16 acc[2][2] = {};

  for (int k0 = 0; k0 < K; k0 += 64) {
#pragma unroll
    for (int h = 0; h < 2; h++)
#pragma unroll
      for (int g16 = 0; g16 < 2; g16++) {
        const int r = (w << 5) + (g16 << 4);
        gload16(A + (long)(m0 + r + srow) * LDA + k0 + (h << 5) + scol, &As[h][r][0]);
        gload16(B + (long)(n0 + r + srow) * LDB + k0 + (h << 5) + scol, &Bs[h][r][0]);
      }
    __syncthreads();

#pragma unroll
    for (int ks = 0; ks < 4; ks++) {
      const int h  = ks >> 1;
      const int cl = ((ks & 1) << 1) + hi;
      const int kc = (cl ^ rsw) << 3;
      f16x8 av[2], bv[2];
#pragma unroll
      for (int i = 0; i < 2; i++)
        av[i] = *(const f16x8*)&As[h][(wy << 6) + (i << 5) + lo5][kc];
#pragma unroll
      for (int j = 0; j < 2; j++)
        bv[j] = *(const f16x8*)&Bs[h][(wx << 6) + (j << 5) + lo5][kc];
#pragma unroll
      for (int i = 0; i < 2; i++)
#pragma unroll
        for (int j = 0; j < 2; j++)
          acc[i][j] = __builtin_amdgcn_mfma_f32_32x32x16_f16(av[i], bv[j], acc[i][j], 0, 0, 0);
    }
    __syncthreads();
  }

  const int rb0 = m0 + (wy << 6) + (hi << 2);
  const int cb0 = n0 + (wx << 6) + lo5;

  if (MODE == 4) {                    // q,k from base cols (N=128)
#pragma unroll
    for (int i = 0; i < 2; i++)
#pragma unroll
      for (int j = 0; j < 2; j++) {
        int jj = cb0 + (j << 5);
        float bias = C0[jj];
        float g0 = C1[jj], g1 = C1[SD + jj];
        float be0 = C2[jj], be1 = C2[SD + jj];
#pragma unroll
        for (int g = 0; g < 4; g++)
#pragma unroll
          for (int rr = 0; rr < 4; rr++) {
            int gr = rb0 + (i << 5) + (g << 3) + rr;
            float s = silu_f(acc[i][j][g * 4 + rr] + bias);
            H2[(long)gr * SD + jj] = (f16)(s * g0 + be0);
            H3[(long)gr * SD + jj] = (f16)(s * g1 + be1);
          }
      }
  } else {                            // MODE 1: sq = (relu(q·k)*64)^2
#pragma unroll
    for (int i = 0; i < 2; i++)
#pragma unroll
      for (int j = 0; j < 2; j++) {
        int gc = cb0 + (j << 5);
#pragma unroll
        for (int g = 0; g < 4; g++)
#pragma unroll
          for (int rr = 0; rr < 4; rr++) {
            int gr = rb0 + (i << 5) + (g << 3) + rr;
            float tv = fmaxf(acc[i][j][g * 4 + rr], 0.f) * 64.f;
            H0[z * (long)S_LEN * S_LEN + (long)gr * S_LEN + gc] = (f16)(tv * tv);
          }
      }
  }
}

extern "C" void kernel_launch(void* const* d_in, const int* in_sizes, int n_in,
                              void* d_out, int out_size, void* d_ws, size_t ws_size,
                              hipStream_t stream) {
  const float* X     = (const float*)d_in[0];
  const float* W_uv  = (const float*)d_in[1];
  const float* b_uv  = (const float*)d_in[2];
  const float* gamma = (const float*)d_in[3];
  const float* beta  = (const float*)d_in[4];
  const float* W_out = (const float*)d_in[5];
  const float* b_out = (const float*)d_in[6];
  float* out = (float*)d_out;

  char* wp = (char*)d_ws;
  f16* Xh   = (f16*)wp; wp += (long)M_TOT * H_DIM * 2;
  f16* Wuvt = (f16*)wp; wp += (long)F_DIM * H_DIM * 2;
  f16* Wt   = (f16*)wp; wp += (long)H_DIM * E_DIM * 2;
  f16* u    = (f16*)wp; wp += (long)M_TOT * E_DIM * 2;
  f16* vt   = (f16*)wp; wp += (long)M_TOT * E_DIM * 2;
  f16* qh   = (f16*)wp; wp += (long)M_TOT * SD * 2;
  f16* kh   = (f16*)wp; wp += (long)M_TOT * SD * 2;
  f16* sq   = (f16*)wp; wp += (long)B_SZ * S_LEN * S_LEN * 2;
  f16* p    = (f16*)wp; wp += (long)M_TOT * E_DIM * 2;

  // prep
  cast_f16_k<<<(M_TOT * H_DIM) / (256 * 4), 256, 0, stream>>>(X, Xh, (long)M_TOT * H_DIM);
  transpose_cast_k<<<dim3(F_DIM / 32, H_DIM / 32), 256, 0, stream>>>(W_uv, Wuvt, H_DIM, F_DIM);
  transpose_cast_k<<<dim3(H_DIM / 32, E_DIM / 32), 256, 0, stream>>>(W_out, Wt, E_DIM, H_DIM);

  // u, v_t  (M=8192, N=4096, K=1024) — 256² 8-phase
  gemm256<0><<<dim3(2 * E_DIM / 256, M_TOT / 256, 1), 512, 0, stream>>>(
      Xh, Wuvt, nullptr, u, vt, nullptr, b_uv);

  // q, k (base 128 cols)
  mfma_gemm<4><<<dim3(1, M_TOT / 128, 1), 256, 0, stream>>>(
      Xh, Wuvt + (long)2 * E_DIM * H_DIM, nullptr, nullptr, nullptr, qh, kh,
      b_uv + 2 * E_DIM, gamma, beta);

  // sq = (relu(q@k^T)*2^6)^2
  mfma_gemm<1><<<dim3(S_LEN / 128, S_LEN / 128, B_SZ), 256, 0, stream>>>(
      qh, kh, nullptr, sq, nullptr, nullptr, nullptr, nullptr, nullptr, nullptr);

  // p = u * (sq @ v)  (M=2048/batch, N=2048, K=2048) — 256² 8-phase
  gemm256<2><<<dim3(E_DIM / 256, S_LEN / 256, B_SZ), 512, 0, stream>>>(
      sq, vt, nullptr, p, nullptr, u, nullptr);

  // out = p @ W_out * 2^-34 + b_out  (M=8192, N=1024, K=2048) — 256² 8-phase
  gemm256<3><<<dim3(H_DIM / 256, M_TOT / 256, 1), 512, 0, stream>>>(
      p, Wt, out, nullptr, nullptr, nullptr, b_out);
}

// Round 3
// 371.308 us; speedup vs baseline: 1.1721x; 1.1721x over previous
//
#include <hip/hip_runtime.h>
#include <stdint.h>

// FLASH — R9 (= R8 resubmit; R8 bench was an infra failure, no counters).
//  256x256 8-phase with fragment register-reuse + 2-bit XOR LDS swizzle.
//  Phase order (ms,ns) = (0,0)->(0,1)->(1,1)->(1,0); each A/B fragment set is
//  read from LDS ONCE per K-tile and register-cached across the two phases
//  that use it (24 ds_read_b128 / wave / K-tile, was 48 in R7).
//  LDS swizzle: physical 16B slot p of row r holds logical chunk
//  p ^ (r&7) ^ ((r>>3)&1); realized writer-side via pre-swizzled global column
//  (global_load_lds LDS dst must stay linear).
//  Staging: every tile stages all 4 halves of tile t+2 (P2: A0,B0; P3: B1;
//  P4: A1); P4 tail s_waitcnt vmcnt(8) — drains exactly tile t+1, keeps tile
//  t+2's 8 loads in flight.  Never vmcnt(0) in the main loop.
//  Modes 1 (K=128) and 4 (N=128) stay on the old 128^2 kernel.

#define H_DIM  1024
#define E_DIM  2048
#define SD     128
#define B_SZ   4
#define S_LEN  2048
#define M_TOT  (B_SZ * S_LEN)          // 8192
#define F_DIM  (2 * E_DIM + SD)        // 4224

typedef _Float16 f16;
typedef __attribute__((ext_vector_type(4))) _Float16 f16x4;
typedef __attribute__((ext_vector_type(8))) _Float16 f16x8;
typedef __attribute__((ext_vector_type(16))) float f32x16;

__device__ __forceinline__ float silu_f(float x) { return x / (1.f + __expf(-x)); }

__device__ __forceinline__ void gload16(const void* g, void* l) {
  __builtin_amdgcn_global_load_lds(
      (const __attribute__((address_space(1))) void*)(uintptr_t)g,
      (__attribute__((address_space(3))) void*)(uint32_t)(uintptr_t)l,
      16, 0, 0);
}

// ---------------- prep kernels ----------------
__global__ __launch_bounds__(256) void cast_f16_k(const float* __restrict__ src,
                                                  f16* __restrict__ dst, long n) {
  long i = ((long)blockIdx.x * 256 + threadIdx.x) * 4;
  if (i < n) {
    float4 v = *(const float4*)(src + i);
    f16x4 h; h[0] = (f16)v.x; h[1] = (f16)v.y; h[2] = (f16)v.z; h[3] = (f16)v.w;
    *(f16x4*)(dst + i) = h;
  }
}

__global__ __launch_bounds__(256) void transpose_cast_k(const float* __restrict__ src,
                                                        f16* __restrict__ dst, int R, int C) {
  __shared__ float tile[32][33];
  int c0 = blockIdx.x * 32, r0 = blockIdx.y * 32;
  int tx = threadIdx.x & 31, ty = threadIdx.x >> 5;
  for (int i = ty; i < 32; i += 8) tile[i][tx] = src[(long)(r0 + i) * C + c0 + tx];
  __syncthreads();
  for (int i = ty; i < 32; i += 8) dst[(long)(c0 + i) * R + r0 + tx] = (f16)tile[tx][i];
}

// ---------------- 256x256 8-phase GEMM ----------------
// A: [m][k] f16 (row stride K), B: [n][k] f16 (row stride K).
//  MODE 0: K=1024, u/v epilogue.  MODE 2: K=2048, p = u*(sq@v^T).
//  MODE 3: K=2048, out fp32 = acc*2^-34 + b_out.
template <int MODE>
__global__ __launch_bounds__(512, 2) void gemm256(
    const f16* __restrict__ Ag, const f16* __restrict__ Bg,
    float* __restrict__ F0, f16* __restrict__ O0, f16* __restrict__ O1,
    const f16* __restrict__ I0, const float* __restrict__ C0)
{
  constexpr int K  = (MODE == 0) ? H_DIM : 2048;
  constexpr int NT = K / 64;

  __shared__ f16 As[2][256][64];   // 64 KB
  __shared__ f16 Bs[2][256][64];   // 64 KB

  const int t    = threadIdx.x;
  const int w    = t >> 6;            // 0..7
  const int lane = t & 63;
  const int lo5  = lane & 31;
  const int hi   = lane >> 5;
  const int wm   = w >> 2;            // 0..1
  const int wn   = w & 3;             // 0..3

  // T1: bijective XCD swizzle (nwg % 8 == 0 for all modes)
  const int gx  = gridDim.x;
  const int nwg = gx * gridDim.y;
  const int lin = blockIdx.y * gx + blockIdx.x;
  const int cpx = nwg >> 3;
  const int wg  = (lin & 7) * cpx + (lin >> 3);
  const int n0  = (wg % gx) * 256;
  const int m0  = (wg / gx) * 256;
  const long z  = blockIdx.z;

  const f16* A = Ag + (MODE == 2 ? z * (long)S_LEN * S_LEN : 0);
  const f16* B = Bg + (MODE == 2 ? z * (long)E_DIM * S_LEN : 0);

  // stage one half-tile (128 rows x 64 k): 2 x gload16 per thread.
  // LDS dst linear; global column pre-swizzled:
  //   logical chunk = (lane&7) ^ (lane>>3) ^ (grp&1)   [= p ^ (r&7) ^ ((r>>3)&1)]
  auto stageA = [&](int bb, int half, int kt2) {
    const f16* g0 = A + (long)(m0 + half * 128) * K + kt2 * 64;
    f16* lb = &As[bb][half * 128][0];
#pragma unroll
    for (int j = 0; j < 2; j++) {
      int grp = (j << 3) + w;                       // 0..15
      int rl  = (grp << 3) + (lane >> 3);           // 0..127
      gload16(g0 + (long)rl * K + (((lane & 7) ^ (lane >> 3) ^ (grp & 1)) << 3),
              lb + (grp << 9));
    }
  };
  auto stageB = [&](int bb, int half, int kt2) {
    const f16* g0 = B + (long)(n0 + half * 128) * K + kt2 * 64;
    f16* lb = &Bs[bb][half * 128][0];
#pragma unroll
    for (int j = 0; j < 2; j++) {
      int grp = (j << 3) + w;
      int rl  = (grp << 3) + (lane >> 3);
      gload16(g0 + (long)rl * K + (((lane & 7) ^ (lane >> 3) ^ (grp & 1)) << 3),
              lb + (grp << 9));
    }
  };

  // acc[q]: q -> (ms = q>>1, ns = q&1)
  f32x16 acc[4][2] = {};
  f16x8 a0[2][4], a1[2][4], b0[4], b1[4];

  const int swz = (lo5 & 7) ^ ((lo5 >> 3) & 1);   // reader row-swizzle term
  const int rA  = wm * 64 + lo5;
  const int rB  = wn * 32 + lo5;

  // prologue: stage tile0 (buf0) and tile1 (buf1) fully; wait tile0; barrier.
  stageA(0, 0, 0); stageA(0, 1, 0); stageB(0, 0, 0); stageB(0, 1, 0);
  stageA(1, 0, 1); stageA(1, 1, 1); stageB(1, 0, 1); stageB(1, 1, 1);
  asm volatile("s_waitcnt vmcnt(8)" ::: "memory");
  __builtin_amdgcn_s_barrier();

  for (int kt = 0; kt < NT; ++kt) {
    const int bf = kt & 1;
    const bool s2 = (kt + 2 < NT);

    // ---- P1: (0,0) — read a0 (A half 0) + b0 (B half 0); no stage
#pragma unroll
    for (int ksl = 0; ksl < 4; ksl++) {
      const int pc = ((((ksl << 1) + hi) ^ swz) << 3);
      a0[0][ksl] = *(const f16x8*)&As[bf][rA][pc];
      a0[1][ksl] = *(const f16x8*)&As[bf][rA + 32][pc];
      b0[ksl]    = *(const f16x8*)&Bs[bf][rB][pc];
    }
    __builtin_amdgcn_s_barrier();
    __builtin_amdgcn_s_setprio(1);
#pragma unroll
    for (int ksl = 0; ksl < 4; ksl++) {
      acc[0][0] = __builtin_amdgcn_mfma_f32_32x32x16_f16(a0[0][ksl], b0[ksl], acc[0][0], 0, 0, 0);
      acc[0][1] = __builtin_amdgcn_mfma_f32_32x32x16_f16(a0[1][ksl], b0[ksl], acc[0][1], 0, 0, 0);
    }
    __builtin_amdgcn_s_setprio(0);
    __builtin_amdgcn_s_barrier();

    // ---- P2: (0,1) — stage t+2:A0,B0 (freed after P1); read b1; reuse a0
    if (s2) { stageA(bf, 0, kt + 2); stageB(bf, 0, kt + 2); }
#pragma unroll
    for (int ksl = 0; ksl < 4; ksl++) {
      const int pc = ((((ksl << 1) + hi) ^ swz) << 3);
      b1[ksl] = *(const f16x8*)&Bs[bf][128 + rB][pc];
    }
    __builtin_amdgcn_s_barrier();
    __builtin_amdgcn_s_setprio(1);
#pragma unroll
    for (int ksl = 0; ksl < 4; ksl++) {
      acc[1][0] = __builtin_amdgcn_mfma_f32_32x32x16_f16(a0[0][ksl], b1[ksl], acc[1][0], 0, 0, 0);
      acc[1][1] = __builtin_amdgcn_mfma_f32_32x32x16_f16(a0[1][ksl], b1[ksl], acc[1][1], 0, 0, 0);
    }
    __builtin_amdgcn_s_setprio(0);
    __builtin_amdgcn_s_barrier();

    // ---- P3: (1,1) — stage t+2:B1 (freed after P2); read a1; reuse b1
    if (s2) stageB(bf, 1, kt + 2);
#pragma unroll
    for (int ksl = 0; ksl < 4; ksl++) {
      const int pc = ((((ksl << 1) + hi) ^ swz) << 3);
      a1[0][ksl] = *(const f16x8*)&As[bf][128 + rA][pc];
      a1[1][ksl] = *(const f16x8*)&As[bf][128 + rA + 32][pc];
    }
    __builtin_amdgcn_s_barrier();
    __builtin_amdgcn_s_setprio(1);
#pragma unroll
    for (int ksl = 0; ksl < 4; ksl++) {
      acc[3][0] = __builtin_amdgcn_mfma_f32_32x32x16_f16(a1[0][ksl], b1[ksl], acc[3][0], 0, 0, 0);
      acc[3][1] = __builtin_amdgcn_mfma_f32_32x32x16_f16(a1[1][ksl], b1[ksl], acc[3][1], 0, 0, 0);
    }
    __builtin_amdgcn_s_setprio(0);
    __builtin_amdgcn_s_barrier();

    // ---- P4: (1,0) — stage t+2:A1 (freed after P3); no reads (a1,b0 in regs)
    if (s2) stageA(bf, 1, kt + 2);
    __builtin_amdgcn_s_barrier();
    __builtin_amdgcn_s_setprio(1);
#pragma unroll
    for (int ksl = 0; ksl < 4; ksl++) {
      acc[2][0] = __builtin_amdgcn_mfma_f32_32x32x16_f16(a1[0][ksl], b0[ksl], acc[2][0], 0, 0, 0);
      acc[2][1] = __builtin_amdgcn_mfma_f32_32x32x16_f16(a1[1][ksl], b0[ksl], acc[2][1], 0, 0, 0);
    }
    __builtin_amdgcn_s_setprio(0);
    if (s2) { asm volatile("s_waitcnt vmcnt(8)" ::: "memory"); }
    else    { asm volatile("s_waitcnt vmcnt(0)" ::: "memory"); }
    __builtin_amdgcn_s_barrier();
  }

  // C/D (32x32): col = lane&31, row = (reg&3) + 8*(reg>>2) + 4*hi
#pragma unroll
  for (int q = 0; q < 4; q++) {
    const int ms = q >> 1;
    const int ns = q & 1;
#pragma unroll
    for (int im = 0; im < 2; im++) {
      const int gc    = n0 + ns * 128 + wn * 32 + lo5;
      const int rbase = m0 + ms * 128 + wm * 64 + im * 32 + (hi << 2);
      if (MODE == 0) {
        const float bias = C0[gc];
        if (n0 < E_DIM) {            // u region: fp16 row-major [M][E]
#pragma unroll
          for (int g = 0; g < 4; g++)
#pragma unroll
            for (int rr = 0; rr < 4; rr++) {
              int gr = rbase + (g << 3) + rr;
              O0[(long)gr * E_DIM + gc] = (f16)silu_f(acc[q][im][g * 4 + rr] + bias);
            }
        } else {                     // v region: fp16 transposed [b][e][s]
#pragma unroll
          for (int g = 0; g < 4; g++) {
            int gr0 = rbase + (g << 3);
            int b   = gr0 >> 11;
            int s0  = gr0 & (S_LEN - 1);
            f16x4 pk;
#pragma unroll
            for (int rr = 0; rr < 4; rr++) pk[rr] = (f16)silu_f(acc[q][im][g * 4 + rr] + bias);
            *(f16x4*)&O1[((long)b * E_DIM + (gc - E_DIM)) * S_LEN + s0] = pk;
          }
        }
      } else if (MODE == 2) {        // p = fp16(u * attn_v_scaled)
        const long rowoff = z * S_LEN;
#pragma unroll
        for (int g = 0; g < 4; g++)
#pragma unroll
          for (int rr = 0; rr < 4; rr++) {
            int gr = rbase + (g << 3) + rr;
            long idx = (rowoff + gr) * (long)E_DIM + gc;
            O0[idx] = (f16)((float)I0[idx] * acc[q][im][g * 4 + rr]);
          }
      } else {                       // MODE 3: out = acc*2^-34 + b_out (fp32)
        const float bias = C0[gc];
#pragma unroll
        for (int g = 0; g < 4; g++)
#pragma unroll
          for (int rr = 0; rr < 4; rr++) {
            int gr = rbase + (g << 3) + rr;
            F0[(long)gr * H_DIM + gc] = acc[q][im][g * 4 + rr] * (1.0f / 17179869184.0f) + bias;
          }
      }
    }
  }
}

// ---------------- old 128x128 kernel (modes 1 and 4 only) ----------------
template <int MODE>
__global__ __launch_bounds__(256) void mfma_gemm(
    const f16* __restrict__ Ag, const f16* __restrict__ Bg,
    float* __restrict__ F0, f16* __restrict__ H0, const f16* __restrict__ H1,
    f16* __restrict__ H2, f16* __restrict__ H3,
    const float* __restrict__ C0, const float* __restrict__ C1,
    const float* __restrict__ C2)
{
  constexpr int K   = (MODE == 1) ? SD : H_DIM;
  constexpr int LDA = K, LDB = K;

  __shared__ f16 As[2][128][32];
  __shared__ f16 Bs[2][128][32];

  const int t    = threadIdx.x;
  const int w    = t >> 6;
  const int lane = t & 63;
  const int lo5  = lane & 31;
  const int hi   = lane >> 5;
  const int wy   = w >> 1, wx = w & 1;
  const int m0   = blockIdx.y * 128;
  const int n0   = blockIdx.x * 128;
  const long z   = blockIdx.z;

  const f16* A = Ag + (MODE == 1 ? z * (long)S_LEN * SD : 0);
  const f16* B = Bg + (MODE == 1 ? z * (long)S_LEN * SD : 0);

  const int srow = lane >> 2;
  const int scol = (((lane & 3) ^ ((srow >> 1) & 3))) * 8;
  const int rsw  = (lo5 >> 1) & 3;

  f32x16 acc[2][2] = {};

  for (int k0 = 0; k0 < K; k0 += 64) {
#pragma unroll
    for (int h = 0; h < 2; h++)
#pragma unroll
      for (int g16 = 0; g16 < 2; g16++) {
        const int r = (w << 5) + (g16 << 4);
        gload16(A + (long)(m0 + r + srow) * LDA + k0 + (h << 5) + scol, &As[h][r][0]);
        gload16(B + (long)(n0 + r + srow) * LDB + k0 + (h << 5) + scol, &Bs[h][r][0]);
      }
    __syncthreads();

#pragma unroll
    for (int ks = 0; ks < 4; ks++) {
      const int h  = ks >> 1;
      const int cl = ((ks & 1) << 1) + hi;
      const int kc = (cl ^ rsw) << 3;
      f16x8 av[2], bv[2];
#pragma unroll
      for (int i = 0; i < 2; i++)
        av[i] = *(const f16x8*)&As[h][(wy << 6) + (i << 5) + lo5][kc];
#pragma unroll
      for (int j = 0; j < 2; j++)
        bv[j] = *(const f16x8*)&Bs[h][(wx << 6) + (j << 5) + lo5][kc];
#pragma unroll
      for (int i = 0; i < 2; i++)
#pragma unroll
        for (int j = 0; j < 2; j++)
          acc[i][j] = __builtin_amdgcn_mfma_f32_32x32x16_f16(av[i], bv[j], acc[i][j], 0, 0, 0);
    }
    __syncthreads();
  }

  const int rb0 = m0 + (wy << 6) + (hi << 2);
  const int cb0 = n0 + (wx << 6) + lo5;

  if (MODE == 4) {                    // q,k from base cols (N=128)
#pragma unroll
    for (int i = 0; i < 2; i++)
#pragma unroll
      for (int j = 0; j < 2; j++) {
        int jj = cb0 + (j << 5);
        float bias = C0[jj];
        float g0 = C1[jj], g1 = C1[SD + jj];
        float be0 = C2[jj], be1 = C2[SD + jj];
#pragma unroll
        for (int g = 0; g < 4; g++)
#pragma unroll
          for (int rr = 0; rr < 4; rr++) {
            int gr = rb0 + (i << 5) + (g << 3) + rr;
            float s = silu_f(acc[i][j][g * 4 + rr] + bias);
            H2[(long)gr * SD + jj] = (f16)(s * g0 + be0);
            H3[(long)gr * SD + jj] = (f16)(s * g1 + be1);
          }
      }
  } else {                            // MODE 1: sq = (relu(q·k)*64)^2
#pragma unroll
    for (int i = 0; i < 2; i++)
#pragma unroll
      for (int j = 0; j < 2; j++) {
        int gc = cb0 + (j << 5);
#pragma unroll
        for (int g = 0; g < 4; g++)
#pragma unroll
          for (int rr = 0; rr < 4; rr++) {
            int gr = rb0 + (i << 5) + (g << 3) + rr;
            float tv = fmaxf(acc[i][j][g * 4 + rr], 0.f) * 64.f;
            H0[z * (long)S_LEN * S_LEN + (long)gr * S_LEN + gc] = (f16)(tv * tv);
          }
      }
  }
}

extern "C" void kernel_launch(void* const* d_in, const int* in_sizes, int n_in,
                              void* d_out, int out_size, void* d_ws, size_t ws_size,
                              hipStream_t stream) {
  const float* X     = (const float*)d_in[0];
  const float* W_uv  = (const float*)d_in[1];
  const float* b_uv  = (const float*)d_in[2];
  const float* gamma = (const float*)d_in[3];
  const float* beta  = (const float*)d_in[4];
  const float* W_out = (const float*)d_in[5];
  const float* b_out = (const float*)d_in[6];
  float* out = (float*)d_out;

  char* wp = (char*)d_ws;
  f16* Xh   = (f16*)wp; wp += (long)M_TOT * H_DIM * 2;
  f16* Wuvt = (f16*)wp; wp += (long)F_DIM * H_DIM * 2;
  f16* Wt   = (f16*)wp; wp += (long)H_DIM * E_DIM * 2;
  f16* u    = (f16*)wp; wp += (long)M_TOT * E_DIM * 2;
  f16* vt   = (f16*)wp; wp += (long)M_TOT * E_DIM * 2;
  f16* qh   = (f16*)wp; wp += (long)M_TOT * SD * 2;
  f16* kh   = (f16*)wp; wp += (long)M_TOT * SD * 2;
  f16* sq   = (f16*)wp; wp += (long)B_SZ * S_LEN * S_LEN * 2;
  f16* p    = (f16*)wp; wp += (long)M_TOT * E_DIM * 2;

  // prep
  cast_f16_k<<<(M_TOT * H_DIM) / (256 * 4), 256, 0, stream>>>(X, Xh, (long)M_TOT * H_DIM);
  transpose_cast_k<<<dim3(F_DIM / 32, H_DIM / 32), 256, 0, stream>>>(W_uv, Wuvt, H_DIM, F_DIM);
  transpose_cast_k<<<dim3(H_DIM / 32, E_DIM / 32), 256, 0, stream>>>(W_out, Wt, E_DIM, H_DIM);

  // u, v_t  (M=8192, N=4096, K=1024) — 256² 8-phase
  gemm256<0><<<dim3(2 * E_DIM / 256, M_TOT / 256, 1), 512, 0, stream>>>(
      Xh, Wuvt, nullptr, u, vt, nullptr, b_uv);

  // q, k (base 128 cols)
  mfma_gemm<4><<<dim3(1, M_TOT / 128, 1), 256, 0, stream>>>(
      Xh, Wuvt + (long)2 * E_DIM * H_DIM, nullptr, nullptr, nullptr, qh, kh,
      b_uv + 2 * E_DIM, gamma, beta);

  // sq = (relu(q@k^T)*2^6)^2
  mfma_gemm<1><<<dim3(S_LEN / 128, S_LEN / 128, B_SZ), 256, 0, stream>>>(
      qh, kh, nullptr, sq, nullptr, nullptr, nullptr, nullptr, nullptr, nullptr);

  // p = u * (sq @ v)  (M=2048/batch, N=2048, K=2048) — 256² 8-phase
  gemm256<2><<<dim3(E_DIM / 256, S_LEN / 256, B_SZ), 512, 0, stream>>>(
      sq, vt, nullptr, p, nullptr, u, nullptr);

  // out = p @ W_out * 2^-34 + b_out  (M=8192, N=1024, K=2048) — 256² 8-phase
  gemm256<3><<<dim3(H_DIM / 256, M_TOT / 256, 1), 512, 0, stream>>>(
      p, Wt, out, nullptr, nullptr, nullptr, b_out);
}